// Round 8
// baseline (466.728 us; speedup 1.0000x reference)
//
#include <hip/hip_runtime.h>
#include <hip/hip_bf16.h>

typedef __attribute__((ext_vector_type(8))) short bf16x8;
typedef __attribute__((ext_vector_type(4))) float f32x4;

#define GQ 16
#define L_IN 4096
#define T_UP 8192
#define CB 1024
#define ZROWS 4098   // 4096 + 1 pad each side
#define UROWS 8198   // 8192 + 3 pad each side

__device__ __forceinline__ void gload16(const void* g, void* l) {
    __builtin_amdgcn_global_load_lds((const __attribute__((address_space(1))) void*)g,
                                     (__attribute__((address_space(3))) void*)l, 16, 0, 0);
}

// Barrier with both-side scheduling + memory fences (keeps reads/stages inside
// their (SB,SB) window; cf. rule 18/21).
#define SBR() do { asm volatile("" ::: "memory");                 \
                   __builtin_amdgcn_sched_barrier(0);             \
                   __builtin_amdgcn_s_barrier();                  \
                   __builtin_amdgcn_sched_barrier(0);             \
                   asm volatile("" ::: "memory"); } while (0)
#define LGKM() do { asm volatile("s_waitcnt lgkmcnt(0)" ::: "memory"); \
                    __builtin_amdgcn_sched_barrier(0); } while (0)
#define VMW(n) do { __builtin_amdgcn_sched_barrier(0); \
                    asm volatile("s_waitcnt vmcnt(" #n ")" ::: "memory"); \
                    __builtin_amdgcn_sched_barrier(0); } while (0)

// 16 MFMA: quadrant (MH, NH) of the wave's 128x64 C tile, K=64 (2 slices)
#define MM(MH, NH) do {                                                          \
    __builtin_amdgcn_s_setprio(1);                                               \
    _Pragma("unroll") for (int j_ = 0; j_ < 4; ++j_)                             \
      _Pragma("unroll") for (int n_ = 0; n_ < 2; ++n_)                           \
        _Pragma("unroll") for (int s_ = 0; s_ < 2; ++s_)                         \
          acc[(MH)*4 + j_][(NH)*2 + n_] = __builtin_amdgcn_mfma_f32_16x16x32_bf16( \
              af[j_][s_], bq[(NH)*2 + n_][s_], acc[(MH)*4 + j_][(NH)*2 + n_],    \
              0, 0, 0);                                                          \
    __builtin_amdgcn_s_setprio(0);                                               \
} while (0)

// ---------------- zero pad rows ----------------
__global__ __launch_bounds__(256) void zero_pads(__hip_bfloat16* __restrict__ zp,
                                                 __hip_bfloat16* __restrict__ zup) {
    int idx = blockIdx.x * 256 + threadIdx.x;
    if (idx < 8192) {
        int b = idx >> 11, rs = (idx >> 10) & 1, c = idx & 1023;
        size_t row = (size_t)b * ZROWS + (rs ? (ZROWS - 1) : 0);
        zp[row * 1024 + c] = __float2bfloat16(0.f);
    } else if (idx < 8192 + 24576) {
        int rem = idx - 8192;
        int b = rem / 6144, r2 = rem % 6144;
        int r6 = r2 >> 10, c = r2 & 1023;
        size_t row = (size_t)b * UROWS + (r6 < 3 ? r6 : (UROWS - 6 + r6));
        zup[row * 1024 + c] = __float2bfloat16(0.f);
    }
}

// ---------------- weight repacks (fp32 -> bf16) ----------------
__global__ __launch_bounds__(256) void repack_up(const float* __restrict__ Wup,
                                                 __hip_bfloat16* __restrict__ Wr) {
    int idx = blockIdx.x * 256 + threadIdx.x;
    int kk = idx >> 20;
    int co = (idx >> 10) & 1023;
    int ci = idx & 1023;
    Wr[idx] = __float2bfloat16(Wup[((ci << 10) + co) * 4 + kk]);
}

__global__ __launch_bounds__(256) void repack_head(const float* __restrict__ Wh,
                                                   __hip_bfloat16* __restrict__ Wr) {
    int idx = blockIdx.x * 256 + threadIdx.x;
    int kk = idx >> 19;
    int rem = idx & ((1 << 19) - 1);
    int o = rem >> 10;
    int ci = rem & 1023;
    Wr[idx] = __float2bfloat16(Wh[(o * 1024 + ci) * 7 + kk]);
}

// ---------------- dequant + project -> z bf16 (padded rows) ----------------
__global__ __launch_bounds__(256) void dequant_project(
    const int* __restrict__ indices, const float* __restrict__ codebooks,
    const float* __restrict__ scales, const float* __restrict__ Wout,
    const float* __restrict__ bout, __hip_bfloat16* __restrict__ z)
{
    __shared__ float w_lds[8192];
    __shared__ float b_lds[1024];
    __shared__ float part[128];
    __shared__ float summed[16];
    int tid = threadIdx.x;
    for (int k = tid; k < 8192; k += 256) w_lds[k] = Wout[k];
    for (int k = tid; k < 1024; k += 256) b_lds[k] = bout[k];
    int p0 = blockIdx.x * 16;
    int b  = p0 >> 12;
    int l0 = p0 & 4095;
    __syncthreads();
    for (int i = 0; i < 16; ++i) {
        int l = l0 + i;
        if (tid < 128) {
            int gq = tid >> 3;
            int d  = tid & 7;
            int idx = indices[(b * GQ + gq) * L_IN + l];
            float v = 0.f;
            if (idx >= 0) {
                int ic = (idx < CB) ? idx : 0;
                v = codebooks[(gq * CB + ic) * 8 + d] * scales[gq * 8 + d];
            }
            part[tid] = v;
        }
        __syncthreads();
        if (tid < 16) {
            int g = tid >> 3, d = tid & 7;
            float s = 0.f;
            for (int q = 0; q < 8; ++q) s += part[(g * 8 + q) * 8 + d];
            summed[tid] = s;
        }
        __syncthreads();
        #pragma unroll
        for (int j = 0; j < 4; ++j) {
            int c = tid + j * 256;
            int g = c >> 9;
            float acc = b_lds[c];
            #pragma unroll
            for (int d = 0; d < 8; ++d)
                acc += summed[g * 8 + d] * w_lds[(g * 8 + d) * 512 + (c & 511)];
            z[((size_t)b * ZROWS + l + 1) * 1024 + c] = __float2bfloat16(acc);
        }
        __syncthreads();
    }
}

// ================= 8-phase 256x256 tile conv kernels =================
// R5-verified skeleton (stage plan, VMW gates, 2 barriers/phase) with
// fragment reads moved one phase early: each phase p's reads are issued
// AFTER phase p-1's MFMA (inside (SB1,SB2) of p-1), drained by phase p's
// lgkmcnt(0) -- a full phase + 2 barriers of slack.
// parts: 0=A-lo 1=A-hi 2=B-lo 3=B-hi. Stage plan/iter (R5):
//   ph1:(2it+1,Ahi) ph2:(2it+2,Blo) ph3:(2it+2,Bhi) ph4:(2it+2,Alo)
//   ph5:(2it+2,Ahi) ph6:(2it+3,Blo) ph7:(2it+3,Bhi) ph8:(2it+3,Alo)
// Gates: VMW(6)@ph4/ph8 (last iter ph4: VMW(0)); every read sits after a
// barrier that follows its data's gate (RAW verified per read); each read
// batch drains >=1 barrier before its LDS half is restaged (WAR).

// ---- conv transpose: A = z (m), B = Wr_up (co), K = 2*1024 ----
__global__ __launch_bounds__(512, 2) void conv_up_mfma(
    const __hip_bfloat16* __restrict__ zp, const __hip_bfloat16* __restrict__ Wr,
    const float* __restrict__ bup, __hip_bfloat16* __restrict__ zup)
{
    __shared__ __hip_bfloat16 Als[2][256][64];
    __shared__ __hip_bfloat16 Bls[2][256][64];
    const int tid = threadIdx.x;
    const int lane = tid & 63;
    const int w = tid >> 6;
    const int wm = w >> 2, wn = w & 3;
    const int l15 = lane & 15, kq = lane >> 4;
    const int m0  = blockIdx.x * 256;
    const int co0 = blockIdx.y * 256;
    const int b = blockIdx.z >> 1, P = blockIdx.z & 1;
    const int NT = 32, NIT = 16;

    const __hip_bfloat16* abase = zp + ((size_t)b * ZROWS + m0 + P) * 1024;
    const __hip_bfloat16* bbase = Wr + ((size_t)P * 1024 + co0) * 1024;

    auto stage = [&](int kt, int part) {
        if (kt >= NT) return;
        const int buf = kt & 1;
        const int j = kt >> 4, ci0 = (kt & 15) << 6;
        const int rb = (part & 1) << 7;
        const __hip_bfloat16* src;
        __hip_bfloat16* dst;
        if (part < 2) { src = abase + ((size_t)j + rb) * 1024 + ci0;
                        dst = &Als[buf][rb][0]; }
        else          { src = bbase + ((size_t)j * 2048 + rb) * 1024 + ci0;
                        dst = &Bls[buf][rb][0]; }
        #pragma unroll
        for (int it = 0; it < 2; ++it) {
            int chunk = it * 512 + tid;
            int row = chunk >> 3, cs = chunk & 7;
            int cq = cs ^ (row & 7);
            gload16(src + (size_t)row * 1024 + cq * 8,
                    (char*)dst + ((it * 512 + (w << 6)) << 4));
        }
    };

    f32x4 acc[8][4];
    const f32x4 z4 = {0.f, 0.f, 0.f, 0.f};
    #pragma unroll
    for (int i = 0; i < 8; ++i)
        #pragma unroll
        for (int j = 0; j < 4; ++j) acc[i][j] = z4;

    bf16x8 af[4][2], bq[4][2];

    auto rdA = [&](int buf, int mh) {
        #pragma unroll
        for (int j = 0; j < 4; ++j)
            #pragma unroll
            for (int sl = 0; sl < 2; ++sl) {
                int row = (wm << 7) + (mh << 6) + j * 16 + l15;
                int ch = (sl * 4 + kq) ^ (row & 7);
                af[j][sl] = *(const bf16x8*)&Als[buf][row][ch * 8];
            }
    };
    auto rdBlo = [&](int buf) {
        #pragma unroll
        for (int nf = 0; nf < 2; ++nf)
            #pragma unroll
            for (int sl = 0; sl < 2; ++sl) {
                int row = (wn << 6) + nf * 16 + l15;
                int ch = (sl * 4 + kq) ^ (row & 7);
                bq[nf][sl] = *(const bf16x8*)&Bls[buf][row][ch * 8];
            }
    };
    auto rdBhi = [&](int buf) {
        #pragma unroll
        for (int nf = 2; nf < 4; ++nf)
            #pragma unroll
            for (int sl = 0; sl < 2; ++sl) {
                int row = (wn << 6) + nf * 16 + l15;
                int ch = (sl * 4 + kq) ^ (row & 7);
                bq[nf][sl] = *(const bf16x8*)&Bls[buf][row][ch * 8];
            }
    };

    // prologue (R5): t0 {Blo,Bhi,Alo,Ahi}; t1 {Blo,Bhi,Alo} (t1-Ahi at ph1)
    stage(0, 2); stage(0, 3); stage(0, 0); stage(0, 1);
    stage(1, 2); stage(1, 3); stage(1, 0);
    VMW(6);
    SBR();
    rdA(0, 0); rdBlo(0);        // for ph1 (T0 gated by prologue VMW+SB)

    for (int it = 0; it < NIT; ++it) {
        const bool lastit = (it == NIT - 1);
        // ph1: consume T0 quadrant (0,0)
        stage(2 * it + 1, 1);
        SBR(); LGKM();          // drains Alo+Blo batch (aged 1 phase)
        MM(0, 0);
        rdBhi(0);               // for ph2
        SBR();
        // ph2
        stage(2 * it + 2, 2);
        SBR(); LGKM();          // drains Bhi
        MM(0, 1);
        rdA(0, 1);              // Ahi T0, for ph3 (overwrites af after last Alo use)
        SBR();
        // ph3
        stage(2 * it + 2, 3);
        SBR(); LGKM();          // drains Ahi
        MM(1, 1);
        SBR();
        // ph4 (gate) -- no lgkm needed (operands drained at ph1/ph3)
        stage(2 * it + 2, 0);
        if (lastit) { VMW(0); } else { VMW(6); }
        SBR();
        MM(1, 0);
        rdA(1, 0); rdBlo(1);    // T1 Alo+Blo for ph5 (gated by ph4 VMW+SB)
        SBR();
        // ph5
        stage(2 * it + 2, 1);
        SBR(); LGKM();
        MM(0, 0);
        rdBhi(1);               // for ph6
        SBR();
        // ph6
        stage(2 * it + 3, 2);
        SBR(); LGKM();
        MM(0, 1);
        rdA(1, 1);              // Ahi T1 for ph7
        SBR();
        // ph7
        stage(2 * it + 3, 3);
        SBR(); LGKM();
        MM(1, 1);
        SBR();
        // ph8 (gate)
        stage(2 * it + 3, 0);
        if (!lastit) { VMW(6); }
        SBR();
        MM(1, 0);
        if (!lastit) { rdA(0, 0); rdBlo(0); }   // T0' for next ph1
        SBR();
    }

    float bias[4];
    #pragma unroll
    for (int nf = 0; nf < 4; ++nf) bias[nf] = bup[co0 + (wn << 6) + nf * 16 + l15];
    const int mbase = m0 + (wm << 7) + (kq << 2);
    const int cob = co0 + (wn << 6) + l15;
    #pragma unroll
    for (int mf = 0; mf < 8; ++mf)
        #pragma unroll
        for (int e = 0; e < 4; ++e) {
            int m = mbase + mf * 16 + e;
            size_t rowoff = ((size_t)b * UROWS + 3 + P + 2 * m) * 1024;
            #pragma unroll
            for (int nf = 0; nf < 4; ++nf)
                zup[rowoff + cob + nf * 16] = __float2bfloat16(acc[mf][nf][e] + bias[nf]);
        }
}

// ---- head conv: A = Wr_h (o), B = zu (t), K = 7*1024 ----
__global__ __launch_bounds__(512, 2) void conv_head_mfma(
    const __hip_bfloat16* __restrict__ zup, const __hip_bfloat16* __restrict__ Wr,
    const float* __restrict__ bh, float* __restrict__ out)
{
    __shared__ __hip_bfloat16 Als[2][256][64];
    __shared__ __hip_bfloat16 Bls[2][256][64];
    const int tid = threadIdx.x;
    const int lane = tid & 63;
    const int w = tid >> 6;
    const int wm = w >> 2, wn = w & 3;
    const int l15 = lane & 15, kq = lane >> 4;
    const int t0 = blockIdx.x * 256;
    const int o0 = blockIdx.y * 256;
    const int b  = blockIdx.z;
    const int NT = 112, NIT = 56;

    const __hip_bfloat16* bbase = zup + ((size_t)b * UROWS + t0) * 1024;

    auto stage = [&](int kt, int part) {
        if (kt >= NT) return;
        const int buf = kt & 1;
        const int kk = kt >> 4, ci0 = (kt & 15) << 6;
        const int rb = (part & 1) << 7;
        const __hip_bfloat16* src;
        __hip_bfloat16* dst;
        if (part < 2) { src = Wr + ((size_t)(kk * 512 + o0 + rb)) * 1024 + ci0;
                        dst = &Als[buf][rb][0]; }
        else          { src = bbase + ((size_t)(kk + rb)) * 1024 + ci0;
                        dst = &Bls[buf][rb][0]; }
        #pragma unroll
        for (int it = 0; it < 2; ++it) {
            int chunk = it * 512 + tid;
            int row = chunk >> 3, cs = chunk & 7;
            int cq = cs ^ (row & 7);
            gload16(src + (size_t)row * 1024 + cq * 8,
                    (char*)dst + ((it * 512 + (w << 6)) << 4));
        }
    };

    f32x4 acc[8][4];
    const f32x4 z4 = {0.f, 0.f, 0.f, 0.f};
    #pragma unroll
    for (int i = 0; i < 8; ++i)
        #pragma unroll
        for (int j = 0; j < 4; ++j) acc[i][j] = z4;

    bf16x8 af[4][2], bq[4][2];

    auto rdA = [&](int buf, int mh) {
        #pragma unroll
        for (int j = 0; j < 4; ++j)
            #pragma unroll
            for (int sl = 0; sl < 2; ++sl) {
                int row = (wm << 7) + (mh << 6) + j * 16 + l15;
                int ch = (sl * 4 + kq) ^ (row & 7);
                af[j][sl] = *(const bf16x8*)&Als[buf][row][ch * 8];
            }
    };
    auto rdBlo = [&](int buf) {
        #pragma unroll
        for (int nf = 0; nf < 2; ++nf)
            #pragma unroll
            for (int sl = 0; sl < 2; ++sl) {
                int row = (wn << 6) + nf * 16 + l15;
                int ch = (sl * 4 + kq) ^ (row & 7);
                bq[nf][sl] = *(const bf16x8*)&Bls[buf][row][ch * 8];
            }
    };
    auto rdBhi = [&](int buf) {
        #pragma unroll
        for (int nf = 2; nf < 4; ++nf)
            #pragma unroll
            for (int sl = 0; sl < 2; ++sl) {
                int row = (wn << 6) + nf * 16 + l15;
                int ch = (sl * 4 + kq) ^ (row & 7);
                bq[nf][sl] = *(const bf16x8*)&Bls[buf][row][ch * 8];
            }
    };

    stage(0, 2); stage(0, 3); stage(0, 0); stage(0, 1);
    stage(1, 2); stage(1, 3); stage(1, 0);
    VMW(6);
    SBR();
    rdA(0, 0); rdBlo(0);

    for (int it = 0; it < NIT; ++it) {
        const bool lastit = (it == NIT - 1);
        // ph1
        stage(2 * it + 1, 1);
        SBR(); LGKM();
        MM(0, 0);
        rdBhi(0);
        SBR();
        // ph2
        stage(2 * it + 2, 2);
        SBR(); LGKM();
        MM(0, 1);
        rdA(0, 1);
        SBR();
        // ph3
        stage(2 * it + 2, 3);
        SBR(); LGKM();
        MM(1, 1);
        SBR();
        // ph4 (gate)
        stage(2 * it + 2, 0);
        if (lastit) { VMW(0); } else { VMW(6); }
        SBR();
        MM(1, 0);
        rdA(1, 0); rdBlo(1);
        SBR();
        // ph5
        stage(2 * it + 2, 1);
        SBR(); LGKM();
        MM(0, 0);
        rdBhi(1);
        SBR();
        // ph6
        stage(2 * it + 3, 2);
        SBR(); LGKM();
        MM(0, 1);
        rdA(1, 1);
        SBR();
        // ph7
        stage(2 * it + 3, 3);
        SBR(); LGKM();
        MM(1, 1);
        SBR();
        // ph8 (gate)
        stage(2 * it + 3, 0);
        if (!lastit) { VMW(6); }
        SBR();
        MM(1, 0);
        if (!lastit) { rdA(0, 0); rdBlo(0); }
        SBR();
    }

    const int obase = o0 + (wm << 7) + (kq << 2);
    const int tbase = t0 + (wn << 6) + l15;
    #pragma unroll
    for (int mf = 0; mf < 8; ++mf)
        #pragma unroll
        for (int e = 0; e < 4; ++e) {
            int o = obase + mf * 16 + e;
            float bias = bh[o];
            size_t rowoff = ((size_t)b * 512 + o) * T_UP + tbase;
            #pragma unroll
            for (int nf = 0; nf < 4; ++nf)
                out[rowoff + nf * 16] = acc[mf][nf][e] + bias;
        }
}

extern "C" void kernel_launch(void* const* d_in, const int* in_sizes, int n_in,
                              void* d_out, int out_size, void* d_ws, size_t ws_size,
                              hipStream_t stream) {
    const int*   indices   = (const int*)d_in[0];
    const float* codebooks = (const float*)d_in[1];
    const float* scales    = (const float*)d_in[2];
    const float* Wout      = (const float*)d_in[3];
    const float* bout      = (const float*)d_in[4];
    const float* Wup       = (const float*)d_in[5];
    const float* bup       = (const float*)d_in[6];
    const float* Wh        = (const float*)d_in[7];
    const float* bh        = (const float*)d_in[8];
    float* out = (float*)d_out;

    __hip_bfloat16* zp    = (__hip_bfloat16*)d_ws;
    __hip_bfloat16* zup   = zp + (size_t)4 * ZROWS * 1024;
    __hip_bfloat16* wr_up = zup + (size_t)4 * UROWS * 1024;
    __hip_bfloat16* wr_h  = wr_up + (size_t)4 * 1024 * 1024;

    zero_pads  <<<dim3(128),   dim3(256), 0, stream>>>(zp, zup);
    repack_up  <<<dim3(16384), dim3(256), 0, stream>>>(Wup, wr_up);
    repack_head<<<dim3(14336), dim3(256), 0, stream>>>(Wh, wr_h);
    dequant_project<<<dim3(1024), dim3(256), 0, stream>>>(indices, codebooks, scales,
                                                          Wout, bout, zp);
    conv_up_mfma  <<<dim3(16, 4, 8), dim3(512), 0, stream>>>(zp, wr_up, bup, zup);
    conv_head_mfma<<<dim3(32, 2, 4), dim3(512), 0, stream>>>(zup, wr_h, bh, out);
}